// Round 5
// baseline (448.710 us; speedup 1.0000x reference)
//
#include <hip/hip_runtime.h>

// ---------------------------------------------------------------------------
// Kernel 0: repack conv2/conv3 weights into [ic*9+tap][oc] linear layout.
// UNCHANGED.
// ---------------------------------------------------------------------------
__global__ __launch_bounds__(256) void repack_kernel(
    const float* __restrict__ cw2, const float* __restrict__ cw3,
    float* __restrict__ packed2, float* __restrict__ packed3)
{
    int t = blockIdx.x * 256 + threadIdx.x;   // grid 72*256 = 18432 = 2*9216
    if (t < 9216) {
        int oc = t & 31, r = t >> 5;          // r = ic*9+tap in [0,288)
        packed2[t] = cw2[oc * 288 + r];
    } else {
        int t2 = t - 9216;
        int oc = t2 & 31, r = t2 >> 5;
        packed3[t2] = cw3[oc * 288 + r];
    }
}

// ---------------------------------------------------------------------------
// Kernel 1: fused conv stack + fused BatchNorm partial-sum epilogue.
// UNCHANGED from r4 (the 313 us / 407-total winner): conv3 wave-compacted
// K-split (wave0=g0 full, wave1=g1 full, wave2 16 lanes, wave3 execz-skip).
// ---------------------------------------------------------------------------
__global__ __launch_bounds__(256)
void fused_conv_kernel(
    const float* __restrict__ x,
    const float* __restrict__ cw1, const float* __restrict__ cb1,
    const float* __restrict__ packed2, const float* __restrict__ cb2,
    const float* __restrict__ packed3, const float* __restrict__ cb3,
    float* __restrict__ out3, float* __restrict__ gstats)
{
    const int img = blockIdx.x;
    const int tid = threadIdx.x;

    __shared__ float A[1220];         // xs1(900)+w1s(288)+b1s(32) | wck2(1152)
    __shared__ float B[8320];         // xs2 (32 x 260) | scratch/xs3/wck3
    __shared__ float b2s[32], b3s[32];

    float* xs1  = A;                  // 900: 30x30 padded image
    float* w1s  = A + 900;            // 288
    float* b1s  = A + 1188;           // 32
    float* wck2 = A;                  // 1152: conv2 4-ic chunk (after conv1)
    float* xs2  = B;                  // 32 planes x 260
    float* sc   = B;                  // reduction scratch head
    float* xs3  = B + 1280;           // 2880: 32 x 90 -> [1280,4160)
    float* wck3 = B + 4160;           // 2304: conv3 8-ic chunk -> [4160,6464)
    float* sc2  = B + 5073;           // pool scratch -> [5102,8320)

    // --- zero xs1 pads + all of B ---
    for (int i = tid; i < 900;  i += 256) xs1[i] = 0.f;
    for (int i = tid; i < 8320; i += 256) B[i] = 0.f;
    __syncthreads();

    // --- stage input image + conv1 weights + biases ---
    for (int i = tid; i < 784; i += 256) {
        int yy = i / 28, xx = i % 28;
        xs1[(yy + 1) * 30 + xx + 1] = x[img * 784 + i];
    }
    for (int i = tid; i < 288; i += 256) {
        int oc = i & 31, tap = i >> 5;
        w1s[i] = cw1[oc * 9 + tap];
    }
    if (tid < 32) { b1s[tid] = cb1[tid]; b2s[tid] = cb2[tid]; b3s[tid] = cb3[tid]; }
    __syncthreads();

    // --- conv1 (1->32) + relu + pool -> xs2 (swizzled) ---
    {
        const int c1 = tid & 31;
        float w1r[9];
        #pragma unroll
        for (int t = 0; t < 9; t++) w1r[t] = w1s[t * 32 + c1];
        const float bias1 = b1s[c1];
        for (int o = tid; o < 32 * 196; o += 256) {
            int p = o >> 5;
            int py = p / 14, px = p % 14;
            int base = (2 * py) * 30 + 2 * px;
            float P[16];
            #pragma unroll
            for (int r = 0; r < 4; r++) {
                float2 u0 = *(const float2*)&xs1[base + r * 30];
                float2 u1 = *(const float2*)&xs1[base + r * 30 + 2];
                P[r * 4 + 0] = u0.x; P[r * 4 + 1] = u0.y;
                P[r * 4 + 2] = u1.x; P[r * 4 + 3] = u1.y;
            }
            float a00 = 0.f, a01 = 0.f, a10 = 0.f, a11 = 0.f;
            #pragma unroll
            for (int ky = 0; ky < 3; ky++)
                #pragma unroll
                for (int kx = 0; kx < 3; kx++) {
                    float w = w1r[ky * 3 + kx];
                    a00 = fmaf(P[ky * 4 + kx],           w, a00);
                    a01 = fmaf(P[ky * 4 + kx + 1],       w, a01);
                    a10 = fmaf(P[(ky + 1) * 4 + kx],     w, a10);
                    a11 = fmaf(P[(ky + 1) * 4 + kx + 1], w, a11);
                }
            float v = fmaxf(fmaxf(fmaxf(a00, a01), fmaxf(a10, a11)) + bias1, 0.f);
            int r = py + 1, col = px + 1;
            xs2[c1 * 260 + r * 16 + ((((col >> 2) + r) & 3) << 2) + (col & 3)] = v;
        }
    }

    // --- conv2: 4oc x 14 cols, K-split-2 over 8 chunks of 4 ic ---
    const int g  = tid >> 7;            // K-group 0..1 (2 waves each)
    const int u  = tid & 127;           // unit; active if u < 112
    const int cb = u & 7, R = u >> 3;   // oc-quad, prepool row 0..13
    const int oc0 = cb * 4;
    const bool act2 = (u < 112);

    float acc[4][14];
    #pragma unroll
    for (int a = 0; a < 4; a++)
        #pragma unroll
        for (int c = 0; c < 14; c++) acc[a][c] = 0.f;

    float pf[5];                        // 1152 = 4.5*256
    #pragma unroll
    for (int k = 0; k < 5; k++) {
        int idx = tid + k * 256;
        pf[k] = (idx < 1152) ? packed2[idx] : 0.f;
    }

    for (int ch = 0; ch < 8; ch++) {
        __syncthreads();                // conv1/xs2 writes + prior wck2 reads done
        #pragma unroll
        for (int k = 0; k < 5; k++) {
            int idx = tid + k * 256;
            if (idx < 1152) wck2[idx] = pf[k];
        }
        if (ch < 7) {
            #pragma unroll
            for (int k = 0; k < 5; k++) {
                int idx = tid + k * 256;
                pf[k] = (idx < 1152) ? packed2[(ch + 1) * 1152 + idx] : 0.f;
            }
        }
        __syncthreads();
        if (act2) {
            #pragma unroll
            for (int d = 0; d < 2; d++) {
                const int ld = g * 2 + d;            // local ic 0..3
                const int ic = ch * 4 + ld;
                const float* wd = &wck2[ld * 288 + oc0];
                const int pb = ic * 260;
                #pragma unroll
                for (int ky = 0; ky < 3; ky++) {
                    const int rp = R + ky;
                    const int rb = pb + rp * 16;
                    float row[16];
                    #pragma unroll
                    for (int q = 0; q < 4; q++) {
                        const float4 t = *(const float4*)&xs2[rb + (((q + rp) & 3) << 2)];
                        row[q * 4 + 0] = t.x; row[q * 4 + 1] = t.y;
                        row[q * 4 + 2] = t.z; row[q * 4 + 3] = t.w;
                    }
                    const float4 wa = *(const float4*)&wd[(ky * 3 + 0) * 32];
                    const float4 wb = *(const float4*)&wd[(ky * 3 + 1) * 32];
                    const float4 wc = *(const float4*)&wd[(ky * 3 + 2) * 32];
                    #pragma unroll
                    for (int c = 0; c < 14; c++) {
                        acc[0][c] = fmaf(row[c],     wa.x, acc[0][c]);
                        acc[1][c] = fmaf(row[c],     wa.y, acc[1][c]);
                        acc[2][c] = fmaf(row[c],     wa.z, acc[2][c]);
                        acc[3][c] = fmaf(row[c],     wa.w, acc[3][c]);
                        acc[0][c] = fmaf(row[c + 1], wb.x, acc[0][c]);
                        acc[1][c] = fmaf(row[c + 1], wb.y, acc[1][c]);
                        acc[2][c] = fmaf(row[c + 1], wb.z, acc[2][c]);
                        acc[3][c] = fmaf(row[c + 1], wb.w, acc[3][c]);
                        acc[0][c] = fmaf(row[c + 2], wc.x, acc[0][c]);
                        acc[1][c] = fmaf(row[c + 2], wc.y, acc[1][c]);
                        acc[2][c] = fmaf(row[c + 2], wc.z, acc[2][c]);
                        acc[3][c] = fmaf(row[c + 2], wc.w, acc[3][c]);
                    }
                }
            }
        }
    }

    // --- conv2 K-reduction (1 round, stride-57 scratch in B head, max 6382) ---
    __syncthreads();                     // all xs2 patch reads done
    if (g == 1 && act2) {
        #pragma unroll
        for (int a = 0; a < 4; a++)
            #pragma unroll
            for (int c = 0; c < 14; c++) sc[u * 57 + a * 14 + c] = acc[a][c];
    }
    __syncthreads();
    if (g == 0 && act2) {
        #pragma unroll
        for (int a = 0; a < 4; a++)
            #pragma unroll
            for (int c = 0; c < 14; c++) acc[a][c] += sc[u * 57 + a * 14 + c];
    }
    __syncthreads();                     // reduction scratch retires

    // --- zero xs3 + pool 14x14->7x7 (register hmax, odd/even R via sc2) ---
    for (int i = tid; i < 2880; i += 256) xs3[i] = 0.f;
    float hm[4][7];
    if (g == 0 && act2) {
        #pragma unroll
        for (int a = 0; a < 4; a++)
            #pragma unroll
            for (int c = 0; c < 7; c++)
                hm[a][c] = fmaxf(acc[a][2 * c], acc[a][2 * c + 1]);
        if (R & 1) {                     // sc2 idx max 111*29+27=3246 -> abs 8319
            #pragma unroll
            for (int a = 0; a < 4; a++)
                #pragma unroll
                for (int c = 0; c < 7; c++) sc2[u * 29 + a * 7 + c] = hm[a][c];
        }
    }
    __syncthreads();
    if (g == 0 && act2 && !(R & 1)) {
        const int py = R >> 1;           // 0..6
        #pragma unroll
        for (int a = 0; a < 4; a++)
            #pragma unroll
            for (int c = 0; c < 7; c++) {
                float v = fmaxf(hm[a][c], sc2[(u + 8) * 29 + a * 7 + c]);
                v = fmaxf(v + b2s[oc0 + a], 0.f);
                xs3[(oc0 + a) * 90 + (py + 1) * 10 + (c + 1)] = v;
            }
    }

    // --- conv3 (32->32, 7x7) + relu + pool(7->3 floor), compacted K-split ---
    const int w3v = tid >> 6;            // wave id 0..3
    const int l3  = tid & 63;            // lane
    int g3, u3;
    bool act3;
    if (w3v < 2)      { g3 = w3v;       u3 = l3;            act3 = true;      }
    else if (w3v == 2){ g3 = (l3 >= 8); u3 = 64 + (l3 & 7); act3 = (l3 < 16); }
    else              { g3 = 0;         u3 = 0;             act3 = false;     }
    const int cq3 = u3 & 7, pos = u3 >> 3;   // oc-quad, pooled pos 0..8
    const int oc30 = cq3 * 4;
    const int py3 = pos / 3, px3 = pos % 3;
    const int base3 = (2 * py3) * 10 + 2 * px3;

    float a3[4][4];
    #pragma unroll
    for (int a = 0; a < 4; a++)
        #pragma unroll
        for (int q = 0; q < 4; q++) a3[a][q] = 0.f;

    float pg[9];                        // 2304 = 9*256
    #pragma unroll
    for (int k = 0; k < 9; k++) pg[k] = packed3[tid + k * 256];

    for (int ch = 0; ch < 4; ch++) {
        __syncthreads();                 // pool/xs3 writes + prior wck3 reads done
        #pragma unroll
        for (int k = 0; k < 9; k++) wck3[tid + k * 256] = pg[k];
        if (ch < 3) {
            #pragma unroll
            for (int k = 0; k < 9; k++) pg[k] = packed3[(ch + 1) * 2304 + tid + k * 256];
        }
        __syncthreads();
        if (act3) {
            #pragma unroll 2
            for (int d = 0; d < 4; d++) {
                const int ld = g3 * 4 + d;
                const int ic = ch * 8 + ld;
                const float* xp = &xs3[ic * 90 + base3];
                float P[16];
                #pragma unroll
                for (int r = 0; r < 4; r++) {
                    float2 u0 = *(const float2*)&xp[r * 10];
                    float2 u1 = *(const float2*)&xp[r * 10 + 2];
                    P[r * 4 + 0] = u0.x; P[r * 4 + 1] = u0.y;
                    P[r * 4 + 2] = u1.x; P[r * 4 + 3] = u1.y;
                }
                const float* wd = &wck3[ld * 288 + oc30];
                #pragma unroll
                for (int tap = 0; tap < 9; tap++) {
                    const int ky = tap / 3, kx = tap % 3;
                    const float4 wv = *(const float4*)&wd[tap * 32];
                    const float x00 = P[ky * 4 + kx];
                    const float x01 = P[ky * 4 + kx + 1];
                    const float x10 = P[(ky + 1) * 4 + kx];
                    const float x11 = P[(ky + 1) * 4 + kx + 1];
                    a3[0][0] = fmaf(x00, wv.x, a3[0][0]); a3[0][1] = fmaf(x01, wv.x, a3[0][1]);
                    a3[0][2] = fmaf(x10, wv.x, a3[0][2]); a3[0][3] = fmaf(x11, wv.x, a3[0][3]);
                    a3[1][0] = fmaf(x00, wv.y, a3[1][0]); a3[1][1] = fmaf(x01, wv.y, a3[1][1]);
                    a3[1][2] = fmaf(x10, wv.y, a3[1][2]); a3[1][3] = fmaf(x11, wv.y, a3[1][3]);
                    a3[2][0] = fmaf(x00, wv.z, a3[2][0]); a3[2][1] = fmaf(x01, wv.z, a3[2][1]);
                    a3[2][2] = fmaf(x10, wv.z, a3[2][2]); a3[2][3] = fmaf(x11, wv.z, a3[2][3]);
                    a3[3][0] = fmaf(x00, wv.w, a3[3][0]); a3[3][1] = fmaf(x01, wv.w, a3[3][1]);
                    a3[3][2] = fmaf(x10, wv.w, a3[3][2]); a3[3][3] = fmaf(x11, wv.w, a3[3][3]);
                }
            }
        }
    }

    // --- conv3 K-reduction (1 round, stride-17 scratch in head, max 1222) ---
    __syncthreads();
    if (g3 == 1 && act3) {
        #pragma unroll
        for (int a = 0; a < 4; a++)
            #pragma unroll
            for (int q = 0; q < 4; q++) sc[u3 * 17 + a * 4 + q] = a3[a][q];
    }
    __syncthreads();
    float rres[4];
    const bool writer = (g3 == 0 && act3);
    if (writer) {
        #pragma unroll
        for (int a = 0; a < 4; a++)
            #pragma unroll
            for (int q = 0; q < 4; q++) a3[a][q] += sc[u3 * 17 + a * 4 + q];
        float4 res;
        #pragma unroll
        for (int a = 0; a < 4; a++) {
            float v = fmaxf(fmaxf(a3[a][0], a3[a][1]), fmaxf(a3[a][2], a3[a][3]));
            rres[a] = fmaxf(v + b3s[oc30 + a], 0.f);
        }
        res.x = rres[0]; res.y = rres[1]; res.z = rres[2]; res.w = rres[3];
        *(float4*)&out3[img * 288 + pos * 32 + oc30] = res;
    }

    // --- fused BN partial sums: single-writer LDS grid then 64 atomics ---
    __syncthreads();                     // sc reads done -> B reusable
    for (int i = tid; i < 576; i += 256) B[i] = 0.f;
    __syncthreads();
    if (writer) {
        #pragma unroll
        for (int a = 0; a < 4; a++) {
            B[pos * 64 + oc30 + a]      = rres[a];
            B[pos * 64 + 32 + oc30 + a] = rres[a] * rres[a];
        }
    }
    __syncthreads();
    if (tid < 64) {
        int c = tid & 31, part = tid >> 5;   // part 0 = S, 1 = SS
        float s = 0.f;
        #pragma unroll
        for (int p = 0; p < 9; p++) s += B[p * 64 + part * 32 + c];
        atomicAdd(&gstats[part * 32 + c], s);
    }
}

// ---------------------------------------------------------------------------
// Kernel 3a: BN-finalize + BN-apply + MLP + argmax + action scatter.
// = r1 mlp kernel through argmax (unchanged FMA order), then a cheap
// per-block scatter: LDS-atomic ticket per example, 3 global atomics per
// block for bucket bases, index write into per-action buckets.
// Selection layers REMOVED (moved to grouped kernel 3b).
// ---------------------------------------------------------------------------
__global__ __launch_bounds__(512) void mlp_argmax_kernel(
    const float* __restrict__ out3, const float* __restrict__ gstats,
    const float* __restrict__ bng, const float* __restrict__ bnb,
    const float* __restrict__ pw1, const float* __restrict__ pb1,
    const float* __restrict__ pw2, const float* __restrict__ pb2,
    const float* __restrict__ pw3, const float* __restrict__ pb3,
    int* __restrict__ cntg, int* __restrict__ idxbuf,
    float* __restrict__ out)
{
    const int tid = threadIdx.x;          // 0..511
    const int img0 = blockIdx.x * 8;

    __shared__ float ysT[288 * 14];       // [j][e], stride 14
    __shared__ float hAT[128 * 14];
    __shared__ float hBT[128 * 14];
    __shared__ float wst[32 * 128];       // staged weight tile / K-reduce scratch
    __shared__ float lgp[48];
    __shared__ int   acts[8];
    __shared__ float sa[32], sb[32];
    __shared__ int   lcnt[3], lbase[3];

    // BN finalize from global atomic sums (redundant per block; ~free)
    if (tid < 32) {
        float S = gstats[tid], SS = gstats[32 + tid];
        const float inv_n = 1.f / (4096.f * 9.f);
        float mean = S * inv_n;
        float var = SS * inv_n - mean * mean;
        float a = bng[tid] * rsqrtf(var + 1e-5f);
        sa[tid] = a;
        sb[tid] = bnb[tid] - a * mean;
    }
    __syncthreads();

    // stage + BN: 8*72 = 576 float4 reads, scatter-transpose into ysT
    for (int it = 0; it < 2; it++) {
        int i4 = it * 512 + tid;
        if (i4 < 576) {
            int e = i4 / 72, jq = i4 - e * 72;
            float4 v = *(const float4*)&out3[(img0 + e) * 288 + jq * 4];
            int j = jq * 4;
            ysT[(j + 0) * 14 + e] = fmaf(sa[(j + 0) & 31], v.x, sb[(j + 0) & 31]);
            ysT[(j + 1) * 14 + e] = fmaf(sa[(j + 1) & 31], v.y, sb[(j + 1) & 31]);
            ysT[(j + 2) * 14 + e] = fmaf(sa[(j + 2) & 31], v.z, sb[(j + 2) & 31]);
            ysT[(j + 3) * 14 + e] = fmaf(sa[(j + 3) & 31], v.w, sb[(j + 3) & 31]);
        }
    }

    const int kg = tid >> 8;              // K-half 0/1 (4 waves each)
    const int t8 = tid & 255;
    const int n4 = t8 & 31;               // neuron quad: n = n4*4 .. n4*4+3
    const int eE = t8 >> 5;               // example 0..7 (half-wave uniform)
    const int j0 = kg * 16;               // per-tile j-half for staged layers
    float acc[4];

    // layer 1: 288 -> 128, relu — K tiled by 32 (staged in wst), K-split-2
    {
        acc[0] = 0.f; acc[1] = 0.f; acc[2] = 0.f; acc[3] = 0.f;
        for (int t = 0; t < 9; t++) {
            __syncthreads();              // first iter also covers ysT staging
            #pragma unroll
            for (int s = 0; s < 2; s++) {
                int idx = s * 512 + tid;  // 1024 float4 slots
                int row = idx >> 5, c4 = idx & 31;
                int k = t * 32 + row;
                int i = (k & 31) * 9 + (k >> 5);
                *(float4*)&wst[row * 128 + c4 * 4] =
                    *(const float4*)&pw1[i * 128 + c4 * 4];
            }
            __syncthreads();
            #pragma unroll
            for (int j = 0; j < 16; j++) {
                float4 w = *(const float4*)&wst[(j0 + j) * 128 + n4 * 4];
                float yv = ysT[(t * 32 + j0 + j) * 14 + eE];
                acc[0] = fmaf(yv, w.x, acc[0]); acc[1] = fmaf(yv, w.y, acc[1]);
                acc[2] = fmaf(yv, w.z, acc[2]); acc[3] = fmaf(yv, w.w, acc[3]);
            }
        }
        __syncthreads();                  // last tile reads done -> wst reusable
        if (kg) *(float4*)&wst[t8 * 4] = make_float4(acc[0], acc[1], acc[2], acc[3]);
        __syncthreads();
        if (!kg) {
            float4 p = *(const float4*)&wst[t8 * 4];
            float4 b = *(const float4*)&pb1[n4 * 4];
            hAT[(n4 * 4 + 0) * 14 + eE] = fmaxf(acc[0] + p.x + b.x, 0.f);
            hAT[(n4 * 4 + 1) * 14 + eE] = fmaxf(acc[1] + p.y + b.y, 0.f);
            hAT[(n4 * 4 + 2) * 14 + eE] = fmaxf(acc[2] + p.z + b.z, 0.f);
            hAT[(n4 * 4 + 3) * 14 + eE] = fmaxf(acc[3] + p.w + b.w, 0.f);
        }
    }

    // layer 2: 128 -> 128, relu — staged tiles, K-split-2
    {
        acc[0] = 0.f; acc[1] = 0.f; acc[2] = 0.f; acc[3] = 0.f;
        for (int t = 0; t < 4; t++) {
            __syncthreads();              // hAT writes + prior wst reads done
            #pragma unroll
            for (int s = 0; s < 2; s++) {
                int idx = s * 512 + tid;
                int row = idx >> 5, c4 = idx & 31;
                int k = t * 32 + row;
                *(float4*)&wst[row * 128 + c4 * 4] =
                    *(const float4*)&pw2[k * 128 + c4 * 4];
            }
            __syncthreads();
            #pragma unroll
            for (int j = 0; j < 16; j++) {
                float4 w = *(const float4*)&wst[(j0 + j) * 128 + n4 * 4];
                float hv = hAT[(t * 32 + j0 + j) * 14 + eE];
                acc[0] = fmaf(hv, w.x, acc[0]); acc[1] = fmaf(hv, w.y, acc[1]);
                acc[2] = fmaf(hv, w.z, acc[2]); acc[3] = fmaf(hv, w.w, acc[3]);
            }
        }
        __syncthreads();
        if (kg) *(float4*)&wst[t8 * 4] = make_float4(acc[0], acc[1], acc[2], acc[3]);
        __syncthreads();
        if (!kg) {
            float4 p = *(const float4*)&wst[t8 * 4];
            float4 b = *(const float4*)&pb2[n4 * 4];
            hBT[(n4 * 4 + 0) * 14 + eE] = fmaxf(acc[0] + p.x + b.x, 0.f);
            hBT[(n4 * 4 + 1) * 14 + eE] = fmaxf(acc[1] + p.y + b.y, 0.f);
            hBT[(n4 * 4 + 2) * 14 + eE] = fmaxf(acc[2] + p.z + b.z, 0.f);
            hBT[(n4 * 4 + 3) * 14 + eE] = fmaxf(acc[3] + p.w + b.w, 0.f);
        }
    }
    __syncthreads();

    // logits 128 -> 3 (+ lcnt init in disjoint thread range)
    if (tid < 48) {
        int pr = tid & 1, eo = tid >> 1;
        int e = eo / 3, o = eo - e * 3;
        float s = pr ? 0.f : pb3[o];
        const int k0 = pr * 64;
        for (int k = k0; k < k0 + 64; k++) s = fmaf(hBT[k * 14 + e], pw3[k * 3 + o], s);
        lgp[tid] = s;
    } else if (tid < 51) {
        lcnt[tid - 48] = 0;
    }
    __syncthreads();
    int tk = 0;
    if (tid < 8) {
        float l0 = lgp[(tid * 3 + 0) * 2] + lgp[(tid * 3 + 0) * 2 + 1];
        float l1 = lgp[(tid * 3 + 1) * 2] + lgp[(tid * 3 + 1) * 2 + 1];
        float l2 = lgp[(tid * 3 + 2) * 2] + lgp[(tid * 3 + 2) * 2 + 1];
        int a = 0; float best = l0;
        if (l1 > best) { best = l1; a = 1; }
        if (l2 > best) { best = l2; a = 2; }
        acts[tid] = a;
        out[4096 * 10 + img0 + tid] = (float)a;
        tk = atomicAdd(&lcnt[a], 1);      // rank within block for action a
    }
    __syncthreads();
    if (tid < 3) lbase[tid] = atomicAdd(&cntg[tid], lcnt[tid]);
    __syncthreads();
    if (tid < 8) {
        int a = acts[tid];
        idxbuf[a * 4096 + lbase[a] + tk] = img0 + tid;
    }
}

// ---------------------------------------------------------------------------
// Kernel 3s: tiny prefix — bucket counts -> block offsets (16 examples/blk).
// ---------------------------------------------------------------------------
__global__ void prefix_kernel(const int* __restrict__ cntg, int* __restrict__ blkoff)
{
    if (threadIdx.x == 0) {
        int n0 = (cntg[0] + 15) >> 4;
        int n1 = (cntg[1] + 15) >> 4;
        int n2 = (cntg[2] + 15) >> 4;
        blkoff[0] = 0;
        blkoff[1] = n0;
        blkoff[2] = n0 + n1;
        blkoff[3] = n0 + n1 + n2;
    }
}

// ---------------------------------------------------------------------------
// Kernel 3b: grouped selection layers. Each block = 16 SAME-EXPERT examples
// (gathered by index). The single expert's sel1/sel2 weights are staged in
// LDS K=64 tiles with register prefetch (conv pattern) -> each weight word
// loaded once per block; L2 request volume drops ~18x vs per-half-wave
// streams. 512 threads: half-wave eE=tid>>5 owns one example, n4=tid&31
// owns a neuron quad; full-K accumulation (no K-split reduce needed).
// ---------------------------------------------------------------------------
__global__ __launch_bounds__(512) void select_grouped_kernel(
    const float* __restrict__ out3, const float* __restrict__ gstats,
    const float* __restrict__ bng, const float* __restrict__ bnb,
    const float* __restrict__ ew1, const float* __restrict__ eb1,
    const float* __restrict__ ew2, const float* __restrict__ eb2,
    const float* __restrict__ ew3, const float* __restrict__ eb3,
    const int* __restrict__ cntg, const int* __restrict__ blkoff,
    const int* __restrict__ idxbuf,
    float* __restrict__ out)
{
    const int tid = threadIdx.x;          // 0..511
    const int b = blockIdx.x;

    const int bo1 = blkoff[1], bo2 = blkoff[2], bo3 = blkoff[3];
    if (b >= bo3) return;
    int a, chunk;
    if (b < bo1)      { a = 0; chunk = b; }
    else if (b < bo2) { a = 1; chunk = b - bo1; }
    else              { a = 2; chunk = b - bo2; }

    __shared__ float ysT[288 * 18];       // [j][e], stride 18 (16 ex + pad)
    __shared__ float hAT[128 * 18];
    __shared__ float hBT[128 * 18];
    __shared__ float wtile[64 * 128];     // 32 KB expert K-tile
    __shared__ float sp[320];
    __shared__ float sa[32], sb[32];
    __shared__ int   gidx[16];

    const int cnt = cntg[a];
    const int s0 = chunk * 16;

    if (tid < 32) {
        float S = gstats[tid], SS = gstats[32 + tid];
        const float inv_n = 1.f / (4096.f * 9.f);
        float mean = S * inv_n;
        float var = SS * inv_n - mean * mean;
        float aa = bng[tid] * rsqrtf(var + 1e-5f);
        sa[tid] = aa;
        sb[tid] = bnb[tid] - aa * mean;
    }
    if (tid < 16) {
        int s = s0 + tid;
        gidx[tid] = idxbuf[a * 4096 + (s < cnt ? s : cnt - 1)];  // clamp pad
    }
    __syncthreads();

    // gather 16 rows of out3 + BN into ysT
    for (int it = 0; it < 3; it++) {
        int i4 = it * 512 + tid;          // 1152 = 16*72 float4 loads
        if (i4 < 1152) {
            int e = i4 / 72, jq = i4 - e * 72;
            float4 v = *(const float4*)&out3[gidx[e] * 288 + jq * 4];
            int j = jq * 4;
            ysT[(j + 0) * 18 + e] = fmaf(sa[(j + 0) & 31], v.x, sb[(j + 0) & 31]);
            ysT[(j + 1) * 18 + e] = fmaf(sa[(j + 1) & 31], v.y, sb[(j + 1) & 31]);
            ysT[(j + 2) * 18 + e] = fmaf(sa[(j + 2) & 31], v.z, sb[(j + 2) & 31]);
            ysT[(j + 3) * 18 + e] = fmaf(sa[(j + 3) & 31], v.w, sb[(j + 3) & 31]);
        }
    }

    const int n4 = tid & 31;
    const int eE = tid >> 5;              // 0..15
    float acc0, acc1, acc2, acc3;

    // ---- selection layer 1: 288 -> 128, K tiles 64,64,64,64,32 ----
    {
        const float* wb = ew1 + a * 36864;
        float4 bb = *(const float4*)&eb1[a * 128 + n4 * 4];
        acc0 = bb.x; acc1 = bb.y; acc2 = bb.z; acc3 = bb.w;

        float4 pfw[4];                    // tile 0 prefetch (2048 slots)
        #pragma unroll
        for (int s = 0; s < 4; s++) {
            int slot = s * 512 + tid;
            int row = slot >> 5, c4 = slot & 31;
            int i = (row & 31) * 9 + (row >> 5);      // k = row (tile 0)
            pfw[s] = *(const float4*)&wb[i * 128 + c4 * 4];
        }

        for (int t = 0; t < 5; t++) {
            const int rows = (t < 4) ? 64 : 32;
            __syncthreads();              // t=0: ysT staged; else prev wtile reads done
            #pragma unroll
            for (int s = 0; s < 4; s++) {
                int slot = s * 512 + tid;
                if (slot < rows * 32) {
                    int row = slot >> 5, c4 = slot & 31;
                    *(float4*)&wtile[row * 128 + c4 * 4] = pfw[s];
                }
            }
            if (t < 4) {
                const int nrows = (t < 3) ? 64 : 32;
                #pragma unroll
                for (int s = 0; s < 4; s++) {
                    int slot = s * 512 + tid;
                    if (slot < nrows * 32) {
                        int row = slot >> 5, c4 = slot & 31;
                        int k = (t + 1) * 64 + row;
                        int i = (k & 31) * 9 + (k >> 5);
                        pfw[s] = *(const float4*)&wb[i * 128 + c4 * 4];
                    }
                }
            }
            __syncthreads();
            const int kb = t * 64;
            for (int r = 0; r < rows; r++) {
                float4 w = *(const float4*)&wtile[r * 128 + n4 * 4];
                float yv = ysT[(kb + r) * 18 + eE];
                acc0 = fmaf(yv, w.x, acc0); acc1 = fmaf(yv, w.y, acc1);
                acc2 = fmaf(yv, w.z, acc2); acc3 = fmaf(yv, w.w, acc3);
            }
        }
        hAT[(n4 * 4 + 0) * 18 + eE] = acc0;
        hAT[(n4 * 4 + 1) * 18 + eE] = acc1;
        hAT[(n4 * 4 + 2) * 18 + eE] = acc2;
        hAT[(n4 * 4 + 3) * 18 + eE] = acc3;
    }

    // ---- selection layer 2: 128 -> 128, K tiles 64,64 ----
    {
        const float* wb = ew2 + a * 16384;
        float4 bb = *(const float4*)&eb2[a * 128 + n4 * 4];
        acc0 = bb.x; acc1 = bb.y; acc2 = bb.z; acc3 = bb.w;

        float4 pfw[4];
        #pragma unroll
        for (int s = 0; s < 4; s++) {
            int slot = s * 512 + tid;
            int row = slot >> 5, c4 = slot & 31;
            pfw[s] = *(const float4*)&wb[row * 128 + c4 * 4];
        }

        for (int t = 0; t < 2; t++) {
            __syncthreads();              // hAT writes + prev wtile reads done
            #pragma unroll
            for (int s = 0; s < 4; s++) {
                int slot = s * 512 + tid;
                int row = slot >> 5, c4 = slot & 31;
                *(float4*)&wtile[row * 128 + c4 * 4] = pfw[s];
            }
            if (t < 1) {
                #pragma unroll
                for (int s = 0; s < 4; s++) {
                    int slot = s * 512 + tid;
                    int row = slot >> 5, c4 = slot & 31;
                    pfw[s] = *(const float4*)&wb[(64 + row) * 128 + c4 * 4];
                }
            }
            __syncthreads();
            const int kb = t * 64;
            for (int r = 0; r < 64; r++) {
                float4 w = *(const float4*)&wtile[r * 128 + n4 * 4];
                float hv = hAT[(kb + r) * 18 + eE];
                acc0 = fmaf(hv, w.x, acc0); acc1 = fmaf(hv, w.y, acc1);
                acc2 = fmaf(hv, w.z, acc2); acc3 = fmaf(hv, w.w, acc3);
            }
        }
        hBT[(n4 * 4 + 0) * 18 + eE] = acc0;
        hBT[(n4 * 4 + 1) * 18 + eE] = acc1;
        hBT[(n4 * 4 + 2) * 18 + eE] = acc2;
        hBT[(n4 * 4 + 3) * 18 + eE] = acc3;
    }
    __syncthreads();

    // ---- selection layer 3: 128 -> 10, 160 (e,o) pairs x 2 K-partials ----
    if (tid < 320) {
        int pr = (tid >= 160) ? 1 : 0;
        int idx = tid - pr * 160;
        int e = idx / 10, o = idx - e * 10;
        const float* w3 = &ew3[a * 1280];
        float s = pr ? 0.f : eb3[a * 10 + o];
        const int k0 = pr * 64;
        for (int k = k0; k < k0 + 64; k++) s = fmaf(hBT[k * 18 + e], w3[k * 10 + o], s);
        sp[tid] = s;
    }
    __syncthreads();
    if (tid < 160) {
        int e = tid / 10, o = tid - e * 10;
        if (s0 + e < cnt) out[gidx[e] * 10 + o] = sp[tid] + sp[tid + 160];
    }
}

// ---------------------------------------------------------------------------
extern "C" void kernel_launch(void* const* d_in, const int* in_sizes, int n_in,
                              void* d_out, int out_size, void* d_ws, size_t ws_size,
                              hipStream_t stream)
{
    const float* x   = (const float*)d_in[0];
    const float* cw1 = (const float*)d_in[1];
    const float* cb1 = (const float*)d_in[2];
    const float* cw2 = (const float*)d_in[3];
    const float* cb2 = (const float*)d_in[4];
    const float* cw3 = (const float*)d_in[5];
    const float* cb3 = (const float*)d_in[6];
    const float* bng = (const float*)d_in[7];
    const float* bnb = (const float*)d_in[8];
    const float* pw1 = (const float*)d_in[9];
    const float* pb1 = (const float*)d_in[10];
    const float* pw2 = (const float*)d_in[11];
    const float* pb2 = (const float*)d_in[12];
    const float* pw3 = (const float*)d_in[13];
    const float* pb3 = (const float*)d_in[14];
    const float* ew1 = (const float*)d_in[15];
    const float* eb1 = (const float*)d_in[16];
    const float* ew2 = (const float*)d_in[17];
    const float* eb2 = (const float*)d_in[18];
    const float* ew3 = (const float*)d_in[19];
    const float* eb3 = (const float*)d_in[20];

    float* out     = (float*)d_out;
    float* out3    = (float*)d_ws;                    // 4096*288
    float* gstats  = out3 + 4096 * 288;               // 64 floats (atomic S/SS)
    int*   cntg    = (int*)(gstats + 64);             // 3 ints (atomic buckets)
    int*   blkoff  = cntg + 3;                        // 4 ints
    float* packed2 = gstats + 80;                     // 9216
    float* packed3 = packed2 + 9216;                  // 9216
    int*   idxbuf  = (int*)(packed3 + 9216);          // 3*4096 ints

    hipMemsetAsync(gstats, 0, 67 * sizeof(float), stream);   // gstats + cntg
    repack_kernel<<<72, 256, 0, stream>>>(cw2, cw3, packed2, packed3);
    fused_conv_kernel<<<4096, 256, 0, stream>>>(x, cw1, cb1, packed2, cb2,
                                                packed3, cb3, out3, gstats);
    mlp_argmax_kernel<<<512, 512, 0, stream>>>(out3, gstats, bng, bnb,
                                               pw1, pb1, pw2, pb2, pw3, pb3,
                                               cntg, idxbuf, out);
    prefix_kernel<<<1, 64, 0, stream>>>(cntg, blkoff);
    select_grouped_kernel<<<258, 512, 0, stream>>>(out3, gstats, bng, bnb,
                                                   ew1, eb1, ew2, eb2, ew3, eb3,
                                                   cntg, blkoff, idxbuf, out);
}

// Round 6
// 425.049 us; speedup vs baseline: 1.0557x; 1.0557x over previous
//
#include <hip/hip_runtime.h>

// ---------------------------------------------------------------------------
// Kernel 0: repack conv2/conv3 weights into [ic*9+tap][oc] linear layout.
// UNCHANGED.
// ---------------------------------------------------------------------------
__global__ __launch_bounds__(256) void repack_kernel(
    const float* __restrict__ cw2, const float* __restrict__ cw3,
    float* __restrict__ packed2, float* __restrict__ packed3)
{
    int t = blockIdx.x * 256 + threadIdx.x;   // grid 72*256 = 18432 = 2*9216
    if (t < 9216) {
        int oc = t & 31, r = t >> 5;          // r = ic*9+tap in [0,288)
        packed2[t] = cw2[oc * 288 + r];
    } else {
        int t2 = t - 9216;
        int oc = t2 & 31, r = t2 >> 5;
        packed3[t2] = cw3[oc * 288 + r];
    }
}

// ---------------------------------------------------------------------------
// Kernel 1: fused conv stack + fused BatchNorm partial-sum epilogue.
// UNCHANGED from r4 (the 313 us / 407-total winner): conv3 wave-compacted
// K-split (wave0=g0 full, wave1=g1 full, wave2 16 lanes, wave3 execz-skip).
// ---------------------------------------------------------------------------
__global__ __launch_bounds__(256)
void fused_conv_kernel(
    const float* __restrict__ x,
    const float* __restrict__ cw1, const float* __restrict__ cb1,
    const float* __restrict__ packed2, const float* __restrict__ cb2,
    const float* __restrict__ packed3, const float* __restrict__ cb3,
    float* __restrict__ out3, float* __restrict__ gstats)
{
    const int img = blockIdx.x;
    const int tid = threadIdx.x;

    __shared__ float A[1220];         // xs1(900)+w1s(288)+b1s(32) | wck2(1152)
    __shared__ float B[8320];         // xs2 (32 x 260) | scratch/xs3/wck3
    __shared__ float b2s[32], b3s[32];

    float* xs1  = A;                  // 900: 30x30 padded image
    float* w1s  = A + 900;            // 288
    float* b1s  = A + 1188;           // 32
    float* wck2 = A;                  // 1152: conv2 4-ic chunk (after conv1)
    float* xs2  = B;                  // 32 planes x 260
    float* sc   = B;                  // reduction scratch head
    float* xs3  = B + 1280;           // 2880: 32 x 90 -> [1280,4160)
    float* wck3 = B + 4160;           // 2304: conv3 8-ic chunk -> [4160,6464)
    float* sc2  = B + 5073;           // pool scratch -> [5102,8320)

    // --- zero xs1 pads + all of B ---
    for (int i = tid; i < 900;  i += 256) xs1[i] = 0.f;
    for (int i = tid; i < 8320; i += 256) B[i] = 0.f;
    __syncthreads();

    // --- stage input image + conv1 weights + biases ---
    for (int i = tid; i < 784; i += 256) {
        int yy = i / 28, xx = i % 28;
        xs1[(yy + 1) * 30 + xx + 1] = x[img * 784 + i];
    }
    for (int i = tid; i < 288; i += 256) {
        int oc = i & 31, tap = i >> 5;
        w1s[i] = cw1[oc * 9 + tap];
    }
    if (tid < 32) { b1s[tid] = cb1[tid]; b2s[tid] = cb2[tid]; b3s[tid] = cb3[tid]; }
    __syncthreads();

    // --- conv1 (1->32) + relu + pool -> xs2 (swizzled) ---
    {
        const int c1 = tid & 31;
        float w1r[9];
        #pragma unroll
        for (int t = 0; t < 9; t++) w1r[t] = w1s[t * 32 + c1];
        const float bias1 = b1s[c1];
        for (int o = tid; o < 32 * 196; o += 256) {
            int p = o >> 5;
            int py = p / 14, px = p % 14;
            int base = (2 * py) * 30 + 2 * px;
            float P[16];
            #pragma unroll
            for (int r = 0; r < 4; r++) {
                float2 u0 = *(const float2*)&xs1[base + r * 30];
                float2 u1 = *(const float2*)&xs1[base + r * 30 + 2];
                P[r * 4 + 0] = u0.x; P[r * 4 + 1] = u0.y;
                P[r * 4 + 2] = u1.x; P[r * 4 + 3] = u1.y;
            }
            float a00 = 0.f, a01 = 0.f, a10 = 0.f, a11 = 0.f;
            #pragma unroll
            for (int ky = 0; ky < 3; ky++)
                #pragma unroll
                for (int kx = 0; kx < 3; kx++) {
                    float w = w1r[ky * 3 + kx];
                    a00 = fmaf(P[ky * 4 + kx],           w, a00);
                    a01 = fmaf(P[ky * 4 + kx + 1],       w, a01);
                    a10 = fmaf(P[(ky + 1) * 4 + kx],     w, a10);
                    a11 = fmaf(P[(ky + 1) * 4 + kx + 1], w, a11);
                }
            float v = fmaxf(fmaxf(fmaxf(a00, a01), fmaxf(a10, a11)) + bias1, 0.f);
            int r = py + 1, col = px + 1;
            xs2[c1 * 260 + r * 16 + ((((col >> 2) + r) & 3) << 2) + (col & 3)] = v;
        }
    }

    // --- conv2: 4oc x 14 cols, K-split-2 over 8 chunks of 4 ic ---
    const int g  = tid >> 7;            // K-group 0..1 (2 waves each)
    const int u  = tid & 127;           // unit; active if u < 112
    const int cb = u & 7, R = u >> 3;   // oc-quad, prepool row 0..13
    const int oc0 = cb * 4;
    const bool act2 = (u < 112);

    float acc[4][14];
    #pragma unroll
    for (int a = 0; a < 4; a++)
        #pragma unroll
        for (int c = 0; c < 14; c++) acc[a][c] = 0.f;

    float pf[5];                        // 1152 = 4.5*256
    #pragma unroll
    for (int k = 0; k < 5; k++) {
        int idx = tid + k * 256;
        pf[k] = (idx < 1152) ? packed2[idx] : 0.f;
    }

    for (int ch = 0; ch < 8; ch++) {
        __syncthreads();                // conv1/xs2 writes + prior wck2 reads done
        #pragma unroll
        for (int k = 0; k < 5; k++) {
            int idx = tid + k * 256;
            if (idx < 1152) wck2[idx] = pf[k];
        }
        if (ch < 7) {
            #pragma unroll
            for (int k = 0; k < 5; k++) {
                int idx = tid + k * 256;
                pf[k] = (idx < 1152) ? packed2[(ch + 1) * 1152 + idx] : 0.f;
            }
        }
        __syncthreads();
        if (act2) {
            #pragma unroll
            for (int d = 0; d < 2; d++) {
                const int ld = g * 2 + d;            // local ic 0..3
                const int ic = ch * 4 + ld;
                const float* wd = &wck2[ld * 288 + oc0];
                const int pb = ic * 260;
                #pragma unroll
                for (int ky = 0; ky < 3; ky++) {
                    const int rp = R + ky;
                    const int rb = pb + rp * 16;
                    float row[16];
                    #pragma unroll
                    for (int q = 0; q < 4; q++) {
                        const float4 t = *(const float4*)&xs2[rb + (((q + rp) & 3) << 2)];
                        row[q * 4 + 0] = t.x; row[q * 4 + 1] = t.y;
                        row[q * 4 + 2] = t.z; row[q * 4 + 3] = t.w;
                    }
                    const float4 wa = *(const float4*)&wd[(ky * 3 + 0) * 32];
                    const float4 wb = *(const float4*)&wd[(ky * 3 + 1) * 32];
                    const float4 wc = *(const float4*)&wd[(ky * 3 + 2) * 32];
                    #pragma unroll
                    for (int c = 0; c < 14; c++) {
                        acc[0][c] = fmaf(row[c],     wa.x, acc[0][c]);
                        acc[1][c] = fmaf(row[c],     wa.y, acc[1][c]);
                        acc[2][c] = fmaf(row[c],     wa.z, acc[2][c]);
                        acc[3][c] = fmaf(row[c],     wa.w, acc[3][c]);
                        acc[0][c] = fmaf(row[c + 1], wb.x, acc[0][c]);
                        acc[1][c] = fmaf(row[c + 1], wb.y, acc[1][c]);
                        acc[2][c] = fmaf(row[c + 1], wb.z, acc[2][c]);
                        acc[3][c] = fmaf(row[c + 1], wb.w, acc[3][c]);
                        acc[0][c] = fmaf(row[c + 2], wc.x, acc[0][c]);
                        acc[1][c] = fmaf(row[c + 2], wc.y, acc[1][c]);
                        acc[2][c] = fmaf(row[c + 2], wc.z, acc[2][c]);
                        acc[3][c] = fmaf(row[c + 2], wc.w, acc[3][c]);
                    }
                }
            }
        }
    }

    // --- conv2 K-reduction (1 round, stride-57 scratch in B head, max 6382) ---
    __syncthreads();                     // all xs2 patch reads done
    if (g == 1 && act2) {
        #pragma unroll
        for (int a = 0; a < 4; a++)
            #pragma unroll
            for (int c = 0; c < 14; c++) sc[u * 57 + a * 14 + c] = acc[a][c];
    }
    __syncthreads();
    if (g == 0 && act2) {
        #pragma unroll
        for (int a = 0; a < 4; a++)
            #pragma unroll
            for (int c = 0; c < 14; c++) acc[a][c] += sc[u * 57 + a * 14 + c];
    }
    __syncthreads();                     // reduction scratch retires

    // --- zero xs3 + pool 14x14->7x7 (register hmax, odd/even R via sc2) ---
    for (int i = tid; i < 2880; i += 256) xs3[i] = 0.f;
    float hm[4][7];
    if (g == 0 && act2) {
        #pragma unroll
        for (int a = 0; a < 4; a++)
            #pragma unroll
            for (int c = 0; c < 7; c++)
                hm[a][c] = fmaxf(acc[a][2 * c], acc[a][2 * c + 1]);
        if (R & 1) {                     // sc2 idx max 111*29+27=3246 -> abs 8319
            #pragma unroll
            for (int a = 0; a < 4; a++)
                #pragma unroll
                for (int c = 0; c < 7; c++) sc2[u * 29 + a * 7 + c] = hm[a][c];
        }
    }
    __syncthreads();
    if (g == 0 && act2 && !(R & 1)) {
        const int py = R >> 1;           // 0..6
        #pragma unroll
        for (int a = 0; a < 4; a++)
            #pragma unroll
            for (int c = 0; c < 7; c++) {
                float v = fmaxf(hm[a][c], sc2[(u + 8) * 29 + a * 7 + c]);
                v = fmaxf(v + b2s[oc0 + a], 0.f);
                xs3[(oc0 + a) * 90 + (py + 1) * 10 + (c + 1)] = v;
            }
    }

    // --- conv3 (32->32, 7x7) + relu + pool(7->3 floor), compacted K-split ---
    const int w3v = tid >> 6;            // wave id 0..3
    const int l3  = tid & 63;            // lane
    int g3, u3;
    bool act3;
    if (w3v < 2)      { g3 = w3v;       u3 = l3;            act3 = true;      }
    else if (w3v == 2){ g3 = (l3 >= 8); u3 = 64 + (l3 & 7); act3 = (l3 < 16); }
    else              { g3 = 0;         u3 = 0;             act3 = false;     }
    const int cq3 = u3 & 7, pos = u3 >> 3;   // oc-quad, pooled pos 0..8
    const int oc30 = cq3 * 4;
    const int py3 = pos / 3, px3 = pos % 3;
    const int base3 = (2 * py3) * 10 + 2 * px3;

    float a3[4][4];
    #pragma unroll
    for (int a = 0; a < 4; a++)
        #pragma unroll
        for (int q = 0; q < 4; q++) a3[a][q] = 0.f;

    float pg[9];                        // 2304 = 9*256
    #pragma unroll
    for (int k = 0; k < 9; k++) pg[k] = packed3[tid + k * 256];

    for (int ch = 0; ch < 4; ch++) {
        __syncthreads();                 // pool/xs3 writes + prior wck3 reads done
        #pragma unroll
        for (int k = 0; k < 9; k++) wck3[tid + k * 256] = pg[k];
        if (ch < 3) {
            #pragma unroll
            for (int k = 0; k < 9; k++) pg[k] = packed3[(ch + 1) * 2304 + tid + k * 256];
        }
        __syncthreads();
        if (act3) {
            #pragma unroll 2
            for (int d = 0; d < 4; d++) {
                const int ld = g3 * 4 + d;
                const int ic = ch * 8 + ld;
                const float* xp = &xs3[ic * 90 + base3];
                float P[16];
                #pragma unroll
                for (int r = 0; r < 4; r++) {
                    float2 u0 = *(const float2*)&xp[r * 10];
                    float2 u1 = *(const float2*)&xp[r * 10 + 2];
                    P[r * 4 + 0] = u0.x; P[r * 4 + 1] = u0.y;
                    P[r * 4 + 2] = u1.x; P[r * 4 + 3] = u1.y;
                }
                const float* wd = &wck3[ld * 288 + oc30];
                #pragma unroll
                for (int tap = 0; tap < 9; tap++) {
                    const int ky = tap / 3, kx = tap % 3;
                    const float4 wv = *(const float4*)&wd[tap * 32];
                    const float x00 = P[ky * 4 + kx];
                    const float x01 = P[ky * 4 + kx + 1];
                    const float x10 = P[(ky + 1) * 4 + kx];
                    const float x11 = P[(ky + 1) * 4 + kx + 1];
                    a3[0][0] = fmaf(x00, wv.x, a3[0][0]); a3[0][1] = fmaf(x01, wv.x, a3[0][1]);
                    a3[0][2] = fmaf(x10, wv.x, a3[0][2]); a3[0][3] = fmaf(x11, wv.x, a3[0][3]);
                    a3[1][0] = fmaf(x00, wv.y, a3[1][0]); a3[1][1] = fmaf(x01, wv.y, a3[1][1]);
                    a3[1][2] = fmaf(x10, wv.y, a3[1][2]); a3[1][3] = fmaf(x11, wv.y, a3[1][3]);
                    a3[2][0] = fmaf(x00, wv.z, a3[2][0]); a3[2][1] = fmaf(x01, wv.z, a3[2][1]);
                    a3[2][2] = fmaf(x10, wv.z, a3[2][2]); a3[2][3] = fmaf(x11, wv.z, a3[2][3]);
                    a3[3][0] = fmaf(x00, wv.w, a3[3][0]); a3[3][1] = fmaf(x01, wv.w, a3[3][1]);
                    a3[3][2] = fmaf(x10, wv.w, a3[3][2]); a3[3][3] = fmaf(x11, wv.w, a3[3][3]);
                }
            }
        }
    }

    // --- conv3 K-reduction (1 round, stride-17 scratch in head, max 1222) ---
    __syncthreads();
    if (g3 == 1 && act3) {
        #pragma unroll
        for (int a = 0; a < 4; a++)
            #pragma unroll
            for (int q = 0; q < 4; q++) sc[u3 * 17 + a * 4 + q] = a3[a][q];
    }
    __syncthreads();
    float rres[4];
    const bool writer = (g3 == 0 && act3);
    if (writer) {
        #pragma unroll
        for (int a = 0; a < 4; a++)
            #pragma unroll
            for (int q = 0; q < 4; q++) a3[a][q] += sc[u3 * 17 + a * 4 + q];
        float4 res;
        #pragma unroll
        for (int a = 0; a < 4; a++) {
            float v = fmaxf(fmaxf(a3[a][0], a3[a][1]), fmaxf(a3[a][2], a3[a][3]));
            rres[a] = fmaxf(v + b3s[oc30 + a], 0.f);
        }
        res.x = rres[0]; res.y = rres[1]; res.z = rres[2]; res.w = rres[3];
        *(float4*)&out3[img * 288 + pos * 32 + oc30] = res;
    }

    // --- fused BN partial sums: single-writer LDS grid then 64 atomics ---
    __syncthreads();                     // sc reads done -> B reusable
    for (int i = tid; i < 576; i += 256) B[i] = 0.f;
    __syncthreads();
    if (writer) {
        #pragma unroll
        for (int a = 0; a < 4; a++) {
            B[pos * 64 + oc30 + a]      = rres[a];
            B[pos * 64 + 32 + oc30 + a] = rres[a] * rres[a];
        }
    }
    __syncthreads();
    if (tid < 64) {
        int c = tid & 31, part = tid >> 5;   // part 0 = S, 1 = SS
        float s = 0.f;
        #pragma unroll
        for (int p = 0; p < 9; p++) s += B[p * 64 + part * 32 + c];
        atomicAdd(&gstats[part * 32 + c], s);
    }
}

// ---------------------------------------------------------------------------
// Kernel 3: BN-finalize + BN-apply + MLP + argmax + 3 selection layers.
// Base = r4/r1 single-kernel tail (measured best). Two changes this round:
// (1) l1/l2 weight tiles K=32 -> K=64 (wst 32 KB): 12 fewer barrier-pairs.
// (2) ACTION-SORTED HALF-WAVES for sel1/sel2: after argmax, an 8-element
//     counting-sort permutation maps half-wave eE -> example perm[eE], so
//     the two half-waves of each wave usually share an expert -> their
//     weight loads have identical addresses and the per-instruction
//     coalescer merges them (≈halves sel L2 requests on matched waves).
//     Per-example FMA chains unchanged -> bit-exact for sel outputs.
// ---------------------------------------------------------------------------
__global__ __launch_bounds__(512) void mlp_select_kernel(
    const float* __restrict__ out3, const float* __restrict__ gstats,
    const float* __restrict__ bng, const float* __restrict__ bnb,
    const float* __restrict__ pw1, const float* __restrict__ pb1,
    const float* __restrict__ pw2, const float* __restrict__ pb2,
    const float* __restrict__ pw3, const float* __restrict__ pb3,
    const float* __restrict__ ew1, const float* __restrict__ eb1,
    const float* __restrict__ ew2, const float* __restrict__ eb2,
    const float* __restrict__ ew3, const float* __restrict__ eb3,
    float* __restrict__ out)
{
    const int tid = threadIdx.x;          // 0..511
    const int img0 = blockIdx.x * 8;

    __shared__ float ysT[288 * 14];       // [j][e], stride 14
    __shared__ float hAT[128 * 14];
    __shared__ float hBT[128 * 14];
    __shared__ float wst[64 * 128];       // staged weight tile (32 KB) / scratch
    __shared__ float lgp[48];
    __shared__ float sp[160];
    __shared__ int   acts[8];
    __shared__ int   perm[8];
    __shared__ float sa[32], sb[32];

    // BN finalize from global atomic sums (redundant per block; ~free)
    if (tid < 32) {
        float S = gstats[tid], SS = gstats[32 + tid];
        const float inv_n = 1.f / (4096.f * 9.f);
        float mean = S * inv_n;
        float var = SS * inv_n - mean * mean;
        float a = bng[tid] * rsqrtf(var + 1e-5f);
        sa[tid] = a;
        sb[tid] = bnb[tid] - a * mean;
    }
    __syncthreads();

    // stage + BN: 8*72 = 576 float4 reads, scatter-transpose into ysT
    for (int it = 0; it < 2; it++) {
        int i4 = it * 512 + tid;
        if (i4 < 576) {
            int e = i4 / 72, jq = i4 - e * 72;
            float4 v = *(const float4*)&out3[(img0 + e) * 288 + jq * 4];
            int j = jq * 4;
            ysT[(j + 0) * 14 + e] = fmaf(sa[(j + 0) & 31], v.x, sb[(j + 0) & 31]);
            ysT[(j + 1) * 14 + e] = fmaf(sa[(j + 1) & 31], v.y, sb[(j + 1) & 31]);
            ysT[(j + 2) * 14 + e] = fmaf(sa[(j + 2) & 31], v.z, sb[(j + 2) & 31]);
            ysT[(j + 3) * 14 + e] = fmaf(sa[(j + 3) & 31], v.w, sb[(j + 3) & 31]);
        }
    }

    const int kg = tid >> 8;              // K-half 0/1 (4 waves each)
    const int t8 = tid & 255;
    const int n4 = t8 & 31;               // neuron quad: n = n4*4 .. n4*4+3
    const int eE = t8 >> 5;               // example slot 0..7 (half-wave uniform)
    float acc[4];

    // layer 1: 288 -> 128, relu — K tiled by 64 (staged in wst), K-split-2
    {
        acc[0] = 0.f; acc[1] = 0.f; acc[2] = 0.f; acc[3] = 0.f;
        for (int t = 0; t < 5; t++) {
            const int rows = (t < 4) ? 64 : 32;
            __syncthreads();              // first iter also covers ysT staging
            #pragma unroll
            for (int s = 0; s < 4; s++) {
                int idx = s * 512 + tid;  // up to 2048 float4 slots
                if (idx < rows * 32) {
                    int row = idx >> 5, c4 = idx & 31;
                    int k = t * 64 + row;
                    int i = (k & 31) * 9 + (k >> 5);
                    *(float4*)&wst[row * 128 + c4 * 4] =
                        *(const float4*)&pw1[i * 128 + c4 * 4];
                }
            }
            __syncthreads();
            const int jc = rows >> 1;     // 32 or 16 per K-half
            const int jb = kg * jc;
            for (int j = 0; j < jc; j++) {
                float4 w = *(const float4*)&wst[(jb + j) * 128 + n4 * 4];
                float yv = ysT[(t * 64 + jb + j) * 14 + eE];
                acc[0] = fmaf(yv, w.x, acc[0]); acc[1] = fmaf(yv, w.y, acc[1]);
                acc[2] = fmaf(yv, w.z, acc[2]); acc[3] = fmaf(yv, w.w, acc[3]);
            }
        }
        __syncthreads();                  // last tile reads done -> wst reusable
        if (kg) *(float4*)&wst[t8 * 4] = make_float4(acc[0], acc[1], acc[2], acc[3]);
        __syncthreads();
        if (!kg) {
            float4 p = *(const float4*)&wst[t8 * 4];
            float4 b = *(const float4*)&pb1[n4 * 4];
            hAT[(n4 * 4 + 0) * 14 + eE] = fmaxf(acc[0] + p.x + b.x, 0.f);
            hAT[(n4 * 4 + 1) * 14 + eE] = fmaxf(acc[1] + p.y + b.y, 0.f);
            hAT[(n4 * 4 + 2) * 14 + eE] = fmaxf(acc[2] + p.z + b.z, 0.f);
            hAT[(n4 * 4 + 3) * 14 + eE] = fmaxf(acc[3] + p.w + b.w, 0.f);
        }
    }

    // layer 2: 128 -> 128, relu — K tiled by 64, K-split-2
    {
        acc[0] = 0.f; acc[1] = 0.f; acc[2] = 0.f; acc[3] = 0.f;
        for (int t = 0; t < 2; t++) {
            __syncthreads();              // hAT writes + prior wst reads done
            #pragma unroll
            for (int s = 0; s < 4; s++) {
                int idx = s * 512 + tid;  // 2048 float4 slots
                int row = idx >> 5, c4 = idx & 31;
                int k = t * 64 + row;
                *(float4*)&wst[row * 128 + c4 * 4] =
                    *(const float4*)&pw2[k * 128 + c4 * 4];
            }
            __syncthreads();
            const int jb = kg * 32;
            for (int j = 0; j < 32; j++) {
                float4 w = *(const float4*)&wst[(jb + j) * 128 + n4 * 4];
                float hv = hAT[(t * 64 + jb + j) * 14 + eE];
                acc[0] = fmaf(hv, w.x, acc[0]); acc[1] = fmaf(hv, w.y, acc[1]);
                acc[2] = fmaf(hv, w.z, acc[2]); acc[3] = fmaf(hv, w.w, acc[3]);
            }
        }
        __syncthreads();
        if (kg) *(float4*)&wst[t8 * 4] = make_float4(acc[0], acc[1], acc[2], acc[3]);
        __syncthreads();
        if (!kg) {
            float4 p = *(const float4*)&wst[t8 * 4];
            float4 b = *(const float4*)&pb2[n4 * 4];
            hBT[(n4 * 4 + 0) * 14 + eE] = fmaxf(acc[0] + p.x + b.x, 0.f);
            hBT[(n4 * 4 + 1) * 14 + eE] = fmaxf(acc[1] + p.y + b.y, 0.f);
            hBT[(n4 * 4 + 2) * 14 + eE] = fmaxf(acc[2] + p.z + b.z, 0.f);
            hBT[(n4 * 4 + 3) * 14 + eE] = fmaxf(acc[3] + p.w + b.w, 0.f);
        }
    }
    __syncthreads();

    // logits 128 -> 3: 24 (e,o) pairs x 2 K-partials of 64 (UNCHANGED order)
    if (tid < 48) {
        int pr = tid & 1, eo = tid >> 1;
        int e = eo / 3, o = eo - e * 3;
        float s = pr ? 0.f : pb3[o];
        const int k0 = pr * 64;
        for (int k = k0; k < k0 + 64; k++) s = fmaf(hBT[k * 14 + e], pw3[k * 3 + o], s);
        lgp[tid] = s;
    }
    __syncthreads();
    if (tid < 8) {
        float l0 = lgp[(tid * 3 + 0) * 2] + lgp[(tid * 3 + 0) * 2 + 1];
        float l1 = lgp[(tid * 3 + 1) * 2] + lgp[(tid * 3 + 1) * 2 + 1];
        float l2 = lgp[(tid * 3 + 2) * 2] + lgp[(tid * 3 + 2) * 2 + 1];
        int a = 0; float best = l0;
        if (l1 > best) { best = l1; a = 1; }
        if (l2 > best) { best = l2; a = 2; }
        acts[tid] = a;
        out[4096 * 10 + img0 + tid] = (float)a;
    }
    __syncthreads();

    // action-sort permutation (8-element counting sort, unique keys)
    if (tid < 8) {
        int my = acts[tid] * 8 + tid;
        int r = 0;
        #pragma unroll
        for (int e2 = 0; e2 < 8; e2++) r += ((acts[e2] * 8 + e2) < my) ? 1 : 0;
        perm[r] = tid;
    }
    __syncthreads();

    const int pE = perm[eE];              // original example for this slot
    const int a = acts[pE];               // half-wave-uniform expert id (sorted)

    // selection layer 1: 288 -> 128, expert stream, K-split-2 (2x144)
    {
        const float* wb = ew1 + a * 36864;
        acc[0] = 0.f; acc[1] = 0.f; acc[2] = 0.f; acc[3] = 0.f;
        const int kb = kg * 144;
        for (int kk = 0; kk < 144; kk++) {
            int k = kb + kk;
            int i = (k & 31) * 9 + (k >> 5);
            float4 w = *(const float4*)&wb[i * 128 + n4 * 4];
            float yv = ysT[k * 14 + pE];
            acc[0] = fmaf(yv, w.x, acc[0]); acc[1] = fmaf(yv, w.y, acc[1]);
            acc[2] = fmaf(yv, w.z, acc[2]); acc[3] = fmaf(yv, w.w, acc[3]);
        }
        __syncthreads();                  // logits-phase hBT reads done; wst free
        if (kg) *(float4*)&wst[t8 * 4] = make_float4(acc[0], acc[1], acc[2], acc[3]);
        __syncthreads();
        if (!kg) {
            float4 p = *(const float4*)&wst[t8 * 4];
            float4 b = *(const float4*)&eb1[a * 128 + n4 * 4];
            hAT[(n4 * 4 + 0) * 14 + eE] = acc[0] + p.x + b.x;
            hAT[(n4 * 4 + 1) * 14 + eE] = acc[1] + p.y + b.y;
            hAT[(n4 * 4 + 2) * 14 + eE] = acc[2] + p.z + b.z;
            hAT[(n4 * 4 + 3) * 14 + eE] = acc[3] + p.w + b.w;
        }
    }
    __syncthreads();

    // selection layer 2: 128 -> 128, expert stream, K-split-2 (2x64)
    {
        const float* wb = ew2 + a * 16384;
        acc[0] = 0.f; acc[1] = 0.f; acc[2] = 0.f; acc[3] = 0.f;
        const int kb = kg * 64;
        for (int kk = 0; kk < 64; kk++) {
            int k = kb + kk;
            float4 w = *(const float4*)&wb[k * 128 + n4 * 4];
            float hv = hAT[k * 14 + eE];
            acc[0] = fmaf(hv, w.x, acc[0]); acc[1] = fmaf(hv, w.y, acc[1]);
            acc[2] = fmaf(hv, w.z, acc[2]); acc[3] = fmaf(hv, w.w, acc[3]);
        }
        __syncthreads();
        if (kg) *(float4*)&wst[t8 * 4] = make_float4(acc[0], acc[1], acc[2], acc[3]);
        __syncthreads();
        if (!kg) {
            float4 p = *(const float4*)&wst[t8 * 4];
            float4 b = *(const float4*)&eb2[a * 128 + n4 * 4];
            hBT[(n4 * 4 + 0) * 14 + eE] = acc[0] + p.x + b.x;
            hBT[(n4 * 4 + 1) * 14 + eE] = acc[1] + p.y + b.y;
            hBT[(n4 * 4 + 2) * 14 + eE] = acc[2] + p.z + b.z;
            hBT[(n4 * 4 + 3) * 14 + eE] = acc[3] + p.w + b.w;
        }
    }
    __syncthreads();

    // selection layer 3: 128 -> 10: 80 (slot,o) pairs x 2 K-partials of 64
    if (tid < 160) {
        int pr = (tid >= 80) ? 1 : 0;
        int idx = tid - pr * 80;
        int e = idx / 10, o = idx - e * 10;   // e = sorted slot
        int aa = acts[perm[e]];
        const float* w3 = &ew3[aa * 1280];
        float s = pr ? 0.f : eb3[aa * 10 + o];
        const int k0 = pr * 64;
        for (int k = k0; k < k0 + 64; k++) s = fmaf(hBT[k * 14 + e], w3[k * 10 + o], s);
        sp[tid] = s;
    }
    __syncthreads();
    if (tid < 80) {
        int e = tid / 10, o = tid - e * 10;   // e = sorted slot
        out[(img0 + perm[e]) * 10 + o] = sp[tid] + sp[tid + 80];
    }
}

// ---------------------------------------------------------------------------
extern "C" void kernel_launch(void* const* d_in, const int* in_sizes, int n_in,
                              void* d_out, int out_size, void* d_ws, size_t ws_size,
                              hipStream_t stream)
{
    const float* x   = (const float*)d_in[0];
    const float* cw1 = (const float*)d_in[1];
    const float* cb1 = (const float*)d_in[2];
    const float* cw2 = (const float*)d_in[3];
    const float* cb2 = (const float*)d_in[4];
    const float* cw3 = (const float*)d_in[5];
    const float* cb3 = (const float*)d_in[6];
    const float* bng = (const float*)d_in[7];
    const float* bnb = (const float*)d_in[8];
    const float* pw1 = (const float*)d_in[9];
    const float* pb1 = (const float*)d_in[10];
    const float* pw2 = (const float*)d_in[11];
    const float* pb2 = (const float*)d_in[12];
    const float* pw3 = (const float*)d_in[13];
    const float* pb3 = (const float*)d_in[14];
    const float* ew1 = (const float*)d_in[15];
    const float* eb1 = (const float*)d_in[16];
    const float* ew2 = (const float*)d_in[17];
    const float* eb2 = (const float*)d_in[18];
    const float* ew3 = (const float*)d_in[19];
    const float* eb3 = (const float*)d_in[20];

    float* out     = (float*)d_out;
    float* out3    = (float*)d_ws;                    // 4096*288
    float* gstats  = out3 + 4096 * 288;               // 64 (atomic S/SS)
    float* packed2 = gstats + 64;                     // 9216
    float* packed3 = packed2 + 9216;                  // 9216

    hipMemsetAsync(gstats, 0, 64 * sizeof(float), stream);
    repack_kernel<<<72, 256, 0, stream>>>(cw2, cw3, packed2, packed3);
    fused_conv_kernel<<<4096, 256, 0, stream>>>(x, cw1, cb1, packed2, cb2,
                                                packed3, cb3, out3, gstats);
    mlp_select_kernel<<<512, 512, 0, stream>>>(out3, gstats, bng, bnb,
                                               pw1, pb1, pw2, pb2, pw3, pb3,
                                               ew1, eb1, ew2, eb2, ew3, eb3, out);
}

// Round 7
// 411.753 us; speedup vs baseline: 1.0898x; 1.0323x over previous
//
#include <hip/hip_runtime.h>

// ---------------------------------------------------------------------------
// Kernel 0: repack conv2/conv3 weights into [ic*9+tap][oc] linear layout.
// UNCHANGED.
// ---------------------------------------------------------------------------
__global__ __launch_bounds__(256) void repack_kernel(
    const float* __restrict__ cw2, const float* __restrict__ cw3,
    float* __restrict__ packed2, float* __restrict__ packed3)
{
    int t = blockIdx.x * 256 + threadIdx.x;   // grid 72*256 = 18432 = 2*9216
    if (t < 9216) {
        int oc = t & 31, r = t >> 5;          // r = ic*9+tap in [0,288)
        packed2[t] = cw2[oc * 288 + r];
    } else {
        int t2 = t - 9216;
        int oc = t2 & 31, r = t2 >> 5;
        packed3[t2] = cw3[oc * 288 + r];
    }
}

// ---------------------------------------------------------------------------
// Kernel 1: fused conv stack + fused BatchNorm partial-sum epilogue.
// UNCHANGED from r4 (the measured winner): conv3 wave-compacted K-split
// (wave0=g0 full, wave1=g1 full, wave2 16 lanes, wave3 execz-skip).
// ---------------------------------------------------------------------------
__global__ __launch_bounds__(256)
void fused_conv_kernel(
    const float* __restrict__ x,
    const float* __restrict__ cw1, const float* __restrict__ cb1,
    const float* __restrict__ packed2, const float* __restrict__ cb2,
    const float* __restrict__ packed3, const float* __restrict__ cb3,
    float* __restrict__ out3, float* __restrict__ gstats)
{
    const int img = blockIdx.x;
    const int tid = threadIdx.x;

    __shared__ float A[1220];         // xs1(900)+w1s(288)+b1s(32) | wck2(1152)
    __shared__ float B[8320];         // xs2 (32 x 260) | scratch/xs3/wck3
    __shared__ float b2s[32], b3s[32];

    float* xs1  = A;                  // 900: 30x30 padded image
    float* w1s  = A + 900;            // 288
    float* b1s  = A + 1188;           // 32
    float* wck2 = A;                  // 1152: conv2 4-ic chunk (after conv1)
    float* xs2  = B;                  // 32 planes x 260
    float* sc   = B;                  // reduction scratch head
    float* xs3  = B + 1280;           // 2880: 32 x 90 -> [1280,4160)
    float* wck3 = B + 4160;           // 2304: conv3 8-ic chunk -> [4160,6464)
    float* sc2  = B + 5073;           // pool scratch -> [5102,8320)

    // --- zero xs1 pads + all of B ---
    for (int i = tid; i < 900;  i += 256) xs1[i] = 0.f;
    for (int i = tid; i < 8320; i += 256) B[i] = 0.f;
    __syncthreads();

    // --- stage input image + conv1 weights + biases ---
    for (int i = tid; i < 784; i += 256) {
        int yy = i / 28, xx = i % 28;
        xs1[(yy + 1) * 30 + xx + 1] = x[img * 784 + i];
    }
    for (int i = tid; i < 288; i += 256) {
        int oc = i & 31, tap = i >> 5;
        w1s[i] = cw1[oc * 9 + tap];
    }
    if (tid < 32) { b1s[tid] = cb1[tid]; b2s[tid] = cb2[tid]; b3s[tid] = cb3[tid]; }
    __syncthreads();

    // --- conv1 (1->32) + relu + pool -> xs2 (swizzled) ---
    {
        const int c1 = tid & 31;
        float w1r[9];
        #pragma unroll
        for (int t = 0; t < 9; t++) w1r[t] = w1s[t * 32 + c1];
        const float bias1 = b1s[c1];
        for (int o = tid; o < 32 * 196; o += 256) {
            int p = o >> 5;
            int py = p / 14, px = p % 14;
            int base = (2 * py) * 30 + 2 * px;
            float P[16];
            #pragma unroll
            for (int r = 0; r < 4; r++) {
                float2 u0 = *(const float2*)&xs1[base + r * 30];
                float2 u1 = *(const float2*)&xs1[base + r * 30 + 2];
                P[r * 4 + 0] = u0.x; P[r * 4 + 1] = u0.y;
                P[r * 4 + 2] = u1.x; P[r * 4 + 3] = u1.y;
            }
            float a00 = 0.f, a01 = 0.f, a10 = 0.f, a11 = 0.f;
            #pragma unroll
            for (int ky = 0; ky < 3; ky++)
                #pragma unroll
                for (int kx = 0; kx < 3; kx++) {
                    float w = w1r[ky * 3 + kx];
                    a00 = fmaf(P[ky * 4 + kx],           w, a00);
                    a01 = fmaf(P[ky * 4 + kx + 1],       w, a01);
                    a10 = fmaf(P[(ky + 1) * 4 + kx],     w, a10);
                    a11 = fmaf(P[(ky + 1) * 4 + kx + 1], w, a11);
                }
            float v = fmaxf(fmaxf(fmaxf(a00, a01), fmaxf(a10, a11)) + bias1, 0.f);
            int r = py + 1, col = px + 1;
            xs2[c1 * 260 + r * 16 + ((((col >> 2) + r) & 3) << 2) + (col & 3)] = v;
        }
    }

    // --- conv2: 4oc x 14 cols, K-split-2 over 8 chunks of 4 ic ---
    const int g  = tid >> 7;            // K-group 0..1 (2 waves each)
    const int u  = tid & 127;           // unit; active if u < 112
    const int cb = u & 7, R = u >> 3;   // oc-quad, prepool row 0..13
    const int oc0 = cb * 4;
    const bool act2 = (u < 112);

    float acc[4][14];
    #pragma unroll
    for (int a = 0; a < 4; a++)
        #pragma unroll
        for (int c = 0; c < 14; c++) acc[a][c] = 0.f;

    float pf[5];                        // 1152 = 4.5*256
    #pragma unroll
    for (int k = 0; k < 5; k++) {
        int idx = tid + k * 256;
        pf[k] = (idx < 1152) ? packed2[idx] : 0.f;
    }

    for (int ch = 0; ch < 8; ch++) {
        __syncthreads();                // conv1/xs2 writes + prior wck2 reads done
        #pragma unroll
        for (int k = 0; k < 5; k++) {
            int idx = tid + k * 256;
            if (idx < 1152) wck2[idx] = pf[k];
        }
        if (ch < 7) {
            #pragma unroll
            for (int k = 0; k < 5; k++) {
                int idx = tid + k * 256;
                pf[k] = (idx < 1152) ? packed2[(ch + 1) * 1152 + idx] : 0.f;
            }
        }
        __syncthreads();
        if (act2) {
            #pragma unroll
            for (int d = 0; d < 2; d++) {
                const int ld = g * 2 + d;            // local ic 0..3
                const int ic = ch * 4 + ld;
                const float* wd = &wck2[ld * 288 + oc0];
                const int pb = ic * 260;
                #pragma unroll
                for (int ky = 0; ky < 3; ky++) {
                    const int rp = R + ky;
                    const int rb = pb + rp * 16;
                    float row[16];
                    #pragma unroll
                    for (int q = 0; q < 4; q++) {
                        const float4 t = *(const float4*)&xs2[rb + (((q + rp) & 3) << 2)];
                        row[q * 4 + 0] = t.x; row[q * 4 + 1] = t.y;
                        row[q * 4 + 2] = t.z; row[q * 4 + 3] = t.w;
                    }
                    const float4 wa = *(const float4*)&wd[(ky * 3 + 0) * 32];
                    const float4 wb = *(const float4*)&wd[(ky * 3 + 1) * 32];
                    const float4 wc = *(const float4*)&wd[(ky * 3 + 2) * 32];
                    #pragma unroll
                    for (int c = 0; c < 14; c++) {
                        acc[0][c] = fmaf(row[c],     wa.x, acc[0][c]);
                        acc[1][c] = fmaf(row[c],     wa.y, acc[1][c]);
                        acc[2][c] = fmaf(row[c],     wa.z, acc[2][c]);
                        acc[3][c] = fmaf(row[c],     wa.w, acc[3][c]);
                        acc[0][c] = fmaf(row[c + 1], wb.x, acc[0][c]);
                        acc[1][c] = fmaf(row[c + 1], wb.y, acc[1][c]);
                        acc[2][c] = fmaf(row[c + 1], wb.z, acc[2][c]);
                        acc[3][c] = fmaf(row[c + 1], wb.w, acc[3][c]);
                        acc[0][c] = fmaf(row[c + 2], wc.x, acc[0][c]);
                        acc[1][c] = fmaf(row[c + 2], wc.y, acc[1][c]);
                        acc[2][c] = fmaf(row[c + 2], wc.z, acc[2][c]);
                        acc[3][c] = fmaf(row[c + 2], wc.w, acc[3][c]);
                    }
                }
            }
        }
    }

    // --- conv2 K-reduction (1 round, stride-57 scratch in B head, max 6382) ---
    __syncthreads();                     // all xs2 patch reads done
    if (g == 1 && act2) {
        #pragma unroll
        for (int a = 0; a < 4; a++)
            #pragma unroll
            for (int c = 0; c < 14; c++) sc[u * 57 + a * 14 + c] = acc[a][c];
    }
    __syncthreads();
    if (g == 0 && act2) {
        #pragma unroll
        for (int a = 0; a < 4; a++)
            #pragma unroll
            for (int c = 0; c < 14; c++) acc[a][c] += sc[u * 57 + a * 14 + c];
    }
    __syncthreads();                     // reduction scratch retires

    // --- zero xs3 + pool 14x14->7x7 (register hmax, odd/even R via sc2) ---
    for (int i = tid; i < 2880; i += 256) xs3[i] = 0.f;
    float hm[4][7];
    if (g == 0 && act2) {
        #pragma unroll
        for (int a = 0; a < 4; a++)
            #pragma unroll
            for (int c = 0; c < 7; c++)
                hm[a][c] = fmaxf(acc[a][2 * c], acc[a][2 * c + 1]);
        if (R & 1) {                     // sc2 idx max 111*29+27=3246 -> abs 8319
            #pragma unroll
            for (int a = 0; a < 4; a++)
                #pragma unroll
                for (int c = 0; c < 7; c++) sc2[u * 29 + a * 7 + c] = hm[a][c];
        }
    }
    __syncthreads();
    if (g == 0 && act2 && !(R & 1)) {
        const int py = R >> 1;           // 0..6
        #pragma unroll
        for (int a = 0; a < 4; a++)
            #pragma unroll
            for (int c = 0; c < 7; c++) {
                float v = fmaxf(hm[a][c], sc2[(u + 8) * 29 + a * 7 + c]);
                v = fmaxf(v + b2s[oc0 + a], 0.f);
                xs3[(oc0 + a) * 90 + (py + 1) * 10 + (c + 1)] = v;
            }
    }

    // --- conv3 (32->32, 7x7) + relu + pool(7->3 floor), compacted K-split ---
    const int w3v = tid >> 6;            // wave id 0..3
    const int l3  = tid & 63;            // lane
    int g3, u3;
    bool act3;
    if (w3v < 2)      { g3 = w3v;       u3 = l3;            act3 = true;      }
    else if (w3v == 2){ g3 = (l3 >= 8); u3 = 64 + (l3 & 7); act3 = (l3 < 16); }
    else              { g3 = 0;         u3 = 0;             act3 = false;     }
    const int cq3 = u3 & 7, pos = u3 >> 3;   // oc-quad, pooled pos 0..8
    const int oc30 = cq3 * 4;
    const int py3 = pos / 3, px3 = pos % 3;
    const int base3 = (2 * py3) * 10 + 2 * px3;

    float a3[4][4];
    #pragma unroll
    for (int a = 0; a < 4; a++)
        #pragma unroll
        for (int q = 0; q < 4; q++) a3[a][q] = 0.f;

    float pg[9];                        // 2304 = 9*256
    #pragma unroll
    for (int k = 0; k < 9; k++) pg[k] = packed3[tid + k * 256];

    for (int ch = 0; ch < 4; ch++) {
        __syncthreads();                 // pool/xs3 writes + prior wck3 reads done
        #pragma unroll
        for (int k = 0; k < 9; k++) wck3[tid + k * 256] = pg[k];
        if (ch < 3) {
            #pragma unroll
            for (int k = 0; k < 9; k++) pg[k] = packed3[(ch + 1) * 2304 + tid + k * 256];
        }
        __syncthreads();
        if (act3) {
            #pragma unroll 2
            for (int d = 0; d < 4; d++) {
                const int ld = g3 * 4 + d;
                const int ic = ch * 8 + ld;
                const float* xp = &xs3[ic * 90 + base3];
                float P[16];
                #pragma unroll
                for (int r = 0; r < 4; r++) {
                    float2 u0 = *(const float2*)&xp[r * 10];
                    float2 u1 = *(const float2*)&xp[r * 10 + 2];
                    P[r * 4 + 0] = u0.x; P[r * 4 + 1] = u0.y;
                    P[r * 4 + 2] = u1.x; P[r * 4 + 3] = u1.y;
                }
                const float* wd = &wck3[ld * 288 + oc30];
                #pragma unroll
                for (int tap = 0; tap < 9; tap++) {
                    const int ky = tap / 3, kx = tap % 3;
                    const float4 wv = *(const float4*)&wd[tap * 32];
                    const float x00 = P[ky * 4 + kx];
                    const float x01 = P[ky * 4 + kx + 1];
                    const float x10 = P[(ky + 1) * 4 + kx];
                    const float x11 = P[(ky + 1) * 4 + kx + 1];
                    a3[0][0] = fmaf(x00, wv.x, a3[0][0]); a3[0][1] = fmaf(x01, wv.x, a3[0][1]);
                    a3[0][2] = fmaf(x10, wv.x, a3[0][2]); a3[0][3] = fmaf(x11, wv.x, a3[0][3]);
                    a3[1][0] = fmaf(x00, wv.y, a3[1][0]); a3[1][1] = fmaf(x01, wv.y, a3[1][1]);
                    a3[1][2] = fmaf(x10, wv.y, a3[1][2]); a3[1][3] = fmaf(x11, wv.y, a3[1][3]);
                    a3[2][0] = fmaf(x00, wv.z, a3[2][0]); a3[2][1] = fmaf(x01, wv.z, a3[2][1]);
                    a3[2][2] = fmaf(x10, wv.z, a3[2][2]); a3[2][3] = fmaf(x11, wv.z, a3[2][3]);
                    a3[3][0] = fmaf(x00, wv.w, a3[3][0]); a3[3][1] = fmaf(x01, wv.w, a3[3][1]);
                    a3[3][2] = fmaf(x10, wv.w, a3[3][2]); a3[3][3] = fmaf(x11, wv.w, a3[3][3]);
                }
            }
        }
    }

    // --- conv3 K-reduction (1 round, stride-17 scratch in head, max 1222) ---
    __syncthreads();
    if (g3 == 1 && act3) {
        #pragma unroll
        for (int a = 0; a < 4; a++)
            #pragma unroll
            for (int q = 0; q < 4; q++) sc[u3 * 17 + a * 4 + q] = a3[a][q];
    }
    __syncthreads();
    float rres[4];
    const bool writer = (g3 == 0 && act3);
    if (writer) {
        #pragma unroll
        for (int a = 0; a < 4; a++)
            #pragma unroll
            for (int q = 0; q < 4; q++) a3[a][q] += sc[u3 * 17 + a * 4 + q];
        float4 res;
        #pragma unroll
        for (int a = 0; a < 4; a++) {
            float v = fmaxf(fmaxf(a3[a][0], a3[a][1]), fmaxf(a3[a][2], a3[a][3]));
            rres[a] = fmaxf(v + b3s[oc30 + a], 0.f);
        }
        res.x = rres[0]; res.y = rres[1]; res.z = rres[2]; res.w = rres[3];
        *(float4*)&out3[img * 288 + pos * 32 + oc30] = res;
    }

    // --- fused BN partial sums: single-writer LDS grid then 64 atomics ---
    __syncthreads();                     // sc reads done -> B reusable
    for (int i = tid; i < 576; i += 256) B[i] = 0.f;
    __syncthreads();
    if (writer) {
        #pragma unroll
        for (int a = 0; a < 4; a++) {
            B[pos * 64 + oc30 + a]      = rres[a];
            B[pos * 64 + 32 + oc30 + a] = rres[a] * rres[a];
        }
    }
    __syncthreads();
    if (tid < 64) {
        int c = tid & 31, part = tid >> 5;   // part 0 = S, 1 = SS
        float s = 0.f;
        #pragma unroll
        for (int p = 0; p < 9; p++) s += B[p * 64 + part * 32 + c];
        atomicAdd(&gstats[part * 32 + c], s);
    }
}

// ---------------------------------------------------------------------------
// Kernel 3: BN-finalize + BN-apply + MLP + argmax + 3 selection layers.
// Base = EXACT r4/r1 tail (measured best ~94 us): K=32 unrolled weight
// tiles, K-split-2 everywhere. ONLY change this round (isolating r6's
// bundle): ACTION-SORTED HALF-WAVES for the selection layers. After argmax,
// an 8-element counting sort maps sorted slot eE -> example perm[eE]; the
// two half-waves of a wave then usually share an expert, so their per-k
// 512B weight loads have identical addresses and merge in the coalescer.
// Per-example FMA chains unchanged -> bit-exact. Cost: 1 barrier + 8-lane
// sort. (r6's K=64 retile with non-unrollable loops is REVERTED - suspected
// cause of the 94->113 us regression.)
// ---------------------------------------------------------------------------
__global__ __launch_bounds__(512) void mlp_select_kernel(
    const float* __restrict__ out3, const float* __restrict__ gstats,
    const float* __restrict__ bng, const float* __restrict__ bnb,
    const float* __restrict__ pw1, const float* __restrict__ pb1,
    const float* __restrict__ pw2, const float* __restrict__ pb2,
    const float* __restrict__ pw3, const float* __restrict__ pb3,
    const float* __restrict__ ew1, const float* __restrict__ eb1,
    const float* __restrict__ ew2, const float* __restrict__ eb2,
    const float* __restrict__ ew3, const float* __restrict__ eb3,
    float* __restrict__ out)
{
    const int tid = threadIdx.x;          // 0..511
    const int img0 = blockIdx.x * 8;

    __shared__ float ysT[288 * 14];       // [j][e], stride 14
    __shared__ float hAT[128 * 14];
    __shared__ float hBT[128 * 14];
    __shared__ float wst[32 * 128];       // staged weight tile / K-reduce scratch
    __shared__ float lgp[48];
    __shared__ float sp[160];
    __shared__ int   acts[8];
    __shared__ int   perm[8];
    __shared__ float sa[32], sb[32];

    // BN finalize from global atomic sums (redundant per block; ~free)
    if (tid < 32) {
        float S = gstats[tid], SS = gstats[32 + tid];
        const float inv_n = 1.f / (4096.f * 9.f);
        float mean = S * inv_n;
        float var = SS * inv_n - mean * mean;
        float a = bng[tid] * rsqrtf(var + 1e-5f);
        sa[tid] = a;
        sb[tid] = bnb[tid] - a * mean;
    }
    __syncthreads();

    // stage + BN: 8*72 = 576 float4 reads, scatter-transpose into ysT
    for (int it = 0; it < 2; it++) {
        int i4 = it * 512 + tid;
        if (i4 < 576) {
            int e = i4 / 72, jq = i4 - e * 72;
            float4 v = *(const float4*)&out3[(img0 + e) * 288 + jq * 4];
            int j = jq * 4;
            ysT[(j + 0) * 14 + e] = fmaf(sa[(j + 0) & 31], v.x, sb[(j + 0) & 31]);
            ysT[(j + 1) * 14 + e] = fmaf(sa[(j + 1) & 31], v.y, sb[(j + 1) & 31]);
            ysT[(j + 2) * 14 + e] = fmaf(sa[(j + 2) & 31], v.z, sb[(j + 2) & 31]);
            ysT[(j + 3) * 14 + e] = fmaf(sa[(j + 3) & 31], v.w, sb[(j + 3) & 31]);
        }
    }

    const int kg = tid >> 8;              // K-half 0/1 (4 waves each)
    const int t8 = tid & 255;
    const int n4 = t8 & 31;               // neuron quad: n = n4*4 .. n4*4+3
    const int eE = t8 >> 5;               // example slot 0..7 (half-wave uniform)
    const int j0 = kg * 16;               // per-tile j-half for staged layers
    float acc[4];

    // layer 1: 288 -> 128, relu — K tiled by 32 (staged in wst), K-split-2
    {
        acc[0] = 0.f; acc[1] = 0.f; acc[2] = 0.f; acc[3] = 0.f;
        for (int t = 0; t < 9; t++) {
            __syncthreads();              // first iter also covers ysT staging
            #pragma unroll
            for (int s = 0; s < 2; s++) {
                int idx = s * 512 + tid;  // 1024 float4 slots
                int row = idx >> 5, c4 = idx & 31;
                int k = t * 32 + row;
                int i = (k & 31) * 9 + (k >> 5);
                *(float4*)&wst[row * 128 + c4 * 4] =
                    *(const float4*)&pw1[i * 128 + c4 * 4];
            }
            __syncthreads();
            #pragma unroll
            for (int j = 0; j < 16; j++) {
                float4 w = *(const float4*)&wst[(j0 + j) * 128 + n4 * 4];
                float yv = ysT[(t * 32 + j0 + j) * 14 + eE];
                acc[0] = fmaf(yv, w.x, acc[0]); acc[1] = fmaf(yv, w.y, acc[1]);
                acc[2] = fmaf(yv, w.z, acc[2]); acc[3] = fmaf(yv, w.w, acc[3]);
            }
        }
        __syncthreads();                  // last tile reads done -> wst reusable
        if (kg) *(float4*)&wst[t8 * 4] = make_float4(acc[0], acc[1], acc[2], acc[3]);
        __syncthreads();
        if (!kg) {
            float4 p = *(const float4*)&wst[t8 * 4];
            float4 b = *(const float4*)&pb1[n4 * 4];
            hAT[(n4 * 4 + 0) * 14 + eE] = fmaxf(acc[0] + p.x + b.x, 0.f);
            hAT[(n4 * 4 + 1) * 14 + eE] = fmaxf(acc[1] + p.y + b.y, 0.f);
            hAT[(n4 * 4 + 2) * 14 + eE] = fmaxf(acc[2] + p.z + b.z, 0.f);
            hAT[(n4 * 4 + 3) * 14 + eE] = fmaxf(acc[3] + p.w + b.w, 0.f);
        }
    }

    // layer 2: 128 -> 128, relu — staged tiles, K-split-2
    {
        acc[0] = 0.f; acc[1] = 0.f; acc[2] = 0.f; acc[3] = 0.f;
        for (int t = 0; t < 4; t++) {
            __syncthreads();              // hAT writes + prior wst reads done
            #pragma unroll
            for (int s = 0; s < 2; s++) {
                int idx = s * 512 + tid;
                int row = idx >> 5, c4 = idx & 31;
                int k = t * 32 + row;
                *(float4*)&wst[row * 128 + c4 * 4] =
                    *(const float4*)&pw2[k * 128 + c4 * 4];
            }
            __syncthreads();
            #pragma unroll
            for (int j = 0; j < 16; j++) {
                float4 w = *(const float4*)&wst[(j0 + j) * 128 + n4 * 4];
                float hv = hAT[(t * 32 + j0 + j) * 14 + eE];
                acc[0] = fmaf(hv, w.x, acc[0]); acc[1] = fmaf(hv, w.y, acc[1]);
                acc[2] = fmaf(hv, w.z, acc[2]); acc[3] = fmaf(hv, w.w, acc[3]);
            }
        }
        __syncthreads();
        if (kg) *(float4*)&wst[t8 * 4] = make_float4(acc[0], acc[1], acc[2], acc[3]);
        __syncthreads();
        if (!kg) {
            float4 p = *(const float4*)&wst[t8 * 4];
            float4 b = *(const float4*)&pb2[n4 * 4];
            hBT[(n4 * 4 + 0) * 14 + eE] = fmaxf(acc[0] + p.x + b.x, 0.f);
            hBT[(n4 * 4 + 1) * 14 + eE] = fmaxf(acc[1] + p.y + b.y, 0.f);
            hBT[(n4 * 4 + 2) * 14 + eE] = fmaxf(acc[2] + p.z + b.z, 0.f);
            hBT[(n4 * 4 + 3) * 14 + eE] = fmaxf(acc[3] + p.w + b.w, 0.f);
        }
    }
    __syncthreads();

    // logits 128 -> 3: 24 (e,o) pairs x 2 K-partials of 64 (UNCHANGED order)
    if (tid < 48) {
        int pr = tid & 1, eo = tid >> 1;
        int e = eo / 3, o = eo - e * 3;
        float s = pr ? 0.f : pb3[o];
        const int k0 = pr * 64;
        for (int k = k0; k < k0 + 64; k++) s = fmaf(hBT[k * 14 + e], pw3[k * 3 + o], s);
        lgp[tid] = s;
    }
    __syncthreads();
    if (tid < 8) {
        float l0 = lgp[(tid * 3 + 0) * 2] + lgp[(tid * 3 + 0) * 2 + 1];
        float l1 = lgp[(tid * 3 + 1) * 2] + lgp[(tid * 3 + 1) * 2 + 1];
        float l2 = lgp[(tid * 3 + 2) * 2] + lgp[(tid * 3 + 2) * 2 + 1];
        int a = 0; float best = l0;
        if (l1 > best) { best = l1; a = 1; }
        if (l2 > best) { best = l2; a = 2; }
        acts[tid] = a;
        out[4096 * 10 + img0 + tid] = (float)a;
    }
    __syncthreads();

    // action-sort permutation (8-element counting sort on stable key)
    if (tid < 8) {
        int my = acts[tid] * 8 + tid;
        int r = 0;
        #pragma unroll
        for (int e2 = 0; e2 < 8; e2++) r += ((acts[e2] * 8 + e2) < my) ? 1 : 0;
        perm[r] = tid;
    }
    __syncthreads();

    const int pE = perm[eE];              // original example for this sorted slot
    const int a = acts[pE];               // half-wave-uniform expert id (sorted)

    // selection layer 1: 288 -> 128, expert stream, K-split-2 (2x144)
    {
        const float* wb = ew1 + a * 36864;
        acc[0] = 0.f; acc[1] = 0.f; acc[2] = 0.f; acc[3] = 0.f;
        const int kb = kg * 144;
        for (int kk = 0; kk < 144; kk++) {
            int k = kb + kk;
            int i = (k & 31) * 9 + (k >> 5);
            float4 w = *(const float4*)&wb[i * 128 + n4 * 4];
            float yv = ysT[k * 14 + pE];
            acc[0] = fmaf(yv, w.x, acc[0]); acc[1] = fmaf(yv, w.y, acc[1]);
            acc[2] = fmaf(yv, w.z, acc[2]); acc[3] = fmaf(yv, w.w, acc[3]);
        }
        __syncthreads();                  // logits-phase hBT reads done; wst free
        if (kg) *(float4*)&wst[t8 * 4] = make_float4(acc[0], acc[1], acc[2], acc[3]);
        __syncthreads();
        if (!kg) {
            float4 p = *(const float4*)&wst[t8 * 4];
            float4 b = *(const float4*)&eb1[a * 128 + n4 * 4];
            hAT[(n4 * 4 + 0) * 14 + eE] = acc[0] + p.x + b.x;
            hAT[(n4 * 4 + 1) * 14 + eE] = acc[1] + p.y + b.y;
            hAT[(n4 * 4 + 2) * 14 + eE] = acc[2] + p.z + b.z;
            hAT[(n4 * 4 + 3) * 14 + eE] = acc[3] + p.w + b.w;
        }
    }
    __syncthreads();

    // selection layer 2: 128 -> 128, expert stream, K-split-2 (2x64)
    {
        const float* wb = ew2 + a * 16384;
        acc[0] = 0.f; acc[1] = 0.f; acc[2] = 0.f; acc[3] = 0.f;
        const int kb = kg * 64;
        for (int kk = 0; kk < 64; kk++) {
            int k = kb + kk;
            float4 w = *(const float4*)&wb[k * 128 + n4 * 4];
            float hv = hAT[k * 14 + eE];
            acc[0] = fmaf(hv, w.x, acc[0]); acc[1] = fmaf(hv, w.y, acc[1]);
            acc[2] = fmaf(hv, w.z, acc[2]); acc[3] = fmaf(hv, w.w, acc[3]);
        }
        __syncthreads();
        if (kg) *(float4*)&wst[t8 * 4] = make_float4(acc[0], acc[1], acc[2], acc[3]);
        __syncthreads();
        if (!kg) {
            float4 p = *(const float4*)&wst[t8 * 4];
            float4 b = *(const float4*)&eb2[a * 128 + n4 * 4];
            hBT[(n4 * 4 + 0) * 14 + eE] = acc[0] + p.x + b.x;
            hBT[(n4 * 4 + 1) * 14 + eE] = acc[1] + p.y + b.y;
            hBT[(n4 * 4 + 2) * 14 + eE] = acc[2] + p.z + b.z;
            hBT[(n4 * 4 + 3) * 14 + eE] = acc[3] + p.w + b.w;
        }
    }
    __syncthreads();

    // selection layer 3: 128 -> 10: 80 (slot,o) pairs x 2 K-partials of 64
    if (tid < 160) {
        int pr = (tid >= 80) ? 1 : 0;
        int idx = tid - pr * 80;
        int e = idx / 10, o = idx - e * 10;   // e = sorted slot
        int aa = acts[perm[e]];
        const float* w3 = &ew3[aa * 1280];
        float s = pr ? 0.f : eb3[aa * 10 + o];
        const int k0 = pr * 64;
        for (int k = k0; k < k0 + 64; k++) s = fmaf(hBT[k * 14 + e], w3[k * 10 + o], s);
        sp[tid] = s;
    }
    __syncthreads();
    if (tid < 80) {
        int e = tid / 10, o = tid - e * 10;   // e = sorted slot
        out[(img0 + perm[e]) * 10 + o] = sp[tid] + sp[tid + 80];
    }
}

// ---------------------------------------------------------------------------
extern "C" void kernel_launch(void* const* d_in, const int* in_sizes, int n_in,
                              void* d_out, int out_size, void* d_ws, size_t ws_size,
                              hipStream_t stream)
{
    const float* x   = (const float*)d_in[0];
    const float* cw1 = (const float*)d_in[1];
    const float* cb1 = (const float*)d_in[2];
    const float* cw2 = (const float*)d_in[3];
    const float* cb2 = (const float*)d_in[4];
    const float* cw3 = (const float*)d_in[5];
    const float* cb3 = (const float*)d_in[6];
    const float* bng = (const float*)d_in[7];
    const float* bnb = (const float*)d_in[8];
    const float* pw1 = (const float*)d_in[9];
    const float* pb1 = (const float*)d_in[10];
    const float* pw2 = (const float*)d_in[11];
    const float* pb2 = (const float*)d_in[12];
    const float* pw3 = (const float*)d_in[13];
    const float* pb3 = (const float*)d_in[14];
    const float* ew1 = (const float*)d_in[15];
    const float* eb1 = (const float*)d_in[16];
    const float* ew2 = (const float*)d_in[17];
    const float* eb2 = (const float*)d_in[18];
    const float* ew3 = (const float*)d_in[19];
    const float* eb3 = (const float*)d_in[20];

    float* out     = (float*)d_out;
    float* out3    = (float*)d_ws;                    // 4096*288
    float* gstats  = out3 + 4096 * 288;               // 64 (atomic S/SS)
    float* packed2 = gstats + 64;                     // 9216
    float* packed3 = packed2 + 9216;                  // 9216

    hipMemsetAsync(gstats, 0, 64 * sizeof(float), stream);
    repack_kernel<<<72, 256, 0, stream>>>(cw2, cw3, packed2, packed3);
    fused_conv_kernel<<<4096, 256, 0, stream>>>(x, cw1, cb1, packed2, cb2,
                                                packed3, cb3, out3, gstats);
    mlp_select_kernel<<<512, 512, 0, stream>>>(out3, gstats, bng, bnb,
                                               pw1, pb1, pw2, pb2, pw3, pb3,
                                               ew1, eb1, ew2, eb2, ew3, eb3, out);
}